// Round 10
// baseline (128.496 us; speedup 1.0000x reference)
//
#include <hip/hip_runtime.h>

#define S_SIGMA 8
#define NBINS   16
#define HDIM    1024
#define WDIM    1024
#define GH      129   // (1024-1)/8 + 2
#define GW      129
#define GZ      17    // NBINS + 1
#define CELLS   (GH*GW*GZ)   // 282897 cells per image
#define ROWSZ   (GW*GZ)      // 2193 float2 per grid row (either layout)
#define EPSV    1e-8f

// ---- gather splat: 2 threads per cell (even/odd rows), REGISTER histogram ----
// 16-bin register hist via unrolled compare-select: no LDS RMW chain in the
// hot loop (round-8 lesson: LDS += serializes; round-7: LDS atomicAdd worse).
__global__ __launch_bounds__(64) void splat_gather_kernel(
    const float* __restrict__ img, float* __restrict__ grid, int nImg, int imgBase)
{
    __shared__ float lval[16 * 64];   // merge buffer only
    __shared__ float lwt [16 * 64];

    int tid = threadIdx.x;
    int c   = tid & 31;          // cell slot
    int h   = tid >> 5;          // row-parity half
    int cellIdx = blockIdx.x * 32 + c;
    int total = nImg * GH * GW;

    float hv[16], hw[16];
    #pragma unroll
    for (int z = 0; z < 16; ++z) { hv[z] = 0.f; hw[z] = 0.f; }

    if (cellIdx < total) {
        int b   = cellIdx / (GH * GW);
        int rem = cellIdx - b * (GH * GW);
        int gy  = rem / GW;
        int gx  = rem - gy * GW;
        const float* ib = img + (size_t)(imgBase + b) * (HDIM * WDIM);

        bool interior = (gx >= 1) & (gx <= 127) & (gy >= 1) & (gy <= 127);
        if (interior) {
            int py = gy & 1, px = gx & 1;
            int ylo = 8 * gy - 4 + py;
            int nr  = 9 - 2 * py;
            int ax  = 8 * gx - 4;           // 4-aligned -> 16B float4 loads
            for (int r = h; r < nr; r += 2) {
                const float* rp = ib + (size_t)(ylo + r) * WDIM + ax;
                float4 A = *(const float4*)rp;
                float4 B = *(const float4*)(rp + 4);
                float  cv = rp[8];
                float e7[7] = {A.y, A.z, A.w, B.x, B.y, B.z, B.w};
                #pragma unroll
                for (int j = 0; j < 7; ++j) {
                    float v = e7[j];
                    int gz = min(max((int)rintf(v * 15.0f), 0), 15);
                    #pragma unroll
                    for (int z = 0; z < 16; ++z) {
                        float m = (gz == z) ? 1.0f : 0.0f;
                        hv[z] = fmaf(m, v, hv[z]);
                        hw[z] += m;
                    }
                }
                if (!px) {   // even gx also owns A.x and cv
                    #pragma unroll
                    for (int e = 0; e < 2; ++e) {
                        float v = e ? cv : A.x;
                        int gz = min(max((int)rintf(v * 15.0f), 0), 15);
                        #pragma unroll
                        for (int z = 0; z < 16; ++z) {
                            float m = (gz == z) ? 1.0f : 0.0f;
                            hv[z] = fmaf(m, v, hv[z]);
                            hw[z] += m;
                        }
                    }
                }
            }
        } else {
            int ylo = max(0, 8 * gy - 4 + (gy & 1));
            int yhi = min(HDIM - 1, 8 * gy + 4 - (gy & 1));
            int xlo = max(0, 8 * gx - 4 + (gx & 1));
            int xhi = min(WDIM - 1, 8 * gx + 4 - (gx & 1));
            for (int y = ylo + h; y <= yhi; y += 2) {
                const float* row = ib + (size_t)y * WDIM;
                for (int x = xlo; x <= xhi; ++x) {
                    float v = row[x];
                    int gz = min(max((int)rintf(v * 15.0f), 0), 15);
                    #pragma unroll
                    for (int z = 0; z < 16; ++z) {
                        float m = (gz == z) ? 1.0f : 0.0f;
                        hv[z] = fmaf(m, v, hv[z]);
                        hw[z] += m;
                    }
                }
            }
        }
    }

    #pragma unroll
    for (int z = 0; z < 16; ++z) { lval[z * 64 + tid] = hv[z]; lwt[z * 64 + tid] = hw[z]; }
    __syncthreads();

    // merge halves; thread h writes z-range [8h, 8h+8). Layout: [gy][gx][z].
    if (cellIdx < total) {
        float2* dst = (float2*)grid + (size_t)cellIdx * GZ;
        int zlo = h * 8, zhi = zlo + 8;
        for (int z = zlo; z < zhi; ++z) {
            float2 o;
            o.x = lval[z * 64 + c] + lval[z * 64 + c + 32];
            o.y = lwt [z * 64 + c] + lwt [z * 64 + c + 32];
            dst[z] = o;
        }
        if (h) { float2 zero; zero.x = 0.f; zero.y = 0.f; dst[16] = zero; }
    }
}

// ---- fused y+x+z blur, LDS tiled; OUTPUT TRANSPOSED to [gy][z][gx] ----
#define TO 12
#define TI 16
#define NIN  (TI*TI*GZ)    // 4352
#define NTMP (TO*TI*GZ)    // 3264
#define NOUT (TO*TO*GZ)    // 2448

__global__ __launch_bounds__(256) void blur_fused_kernel(
    const float2* __restrict__ in, float2* __restrict__ out,
    const float* __restrict__ kfs, const float* __restrict__ kfr)
{
    __shared__ float2 sbin[NIN];
    __shared__ float2 stmp[NTMP];

    int tid = threadIdx.x;
    int tx0 = blockIdx.x * TO;
    int ty0 = blockIdx.y * TO;
    int b   = blockIdx.z;

    float ks[5] = {kfs[0], kfs[1], kfs[2], kfs[3], kfs[4]};
    float kr[5] = {kfr[0], kfr[1], kfr[2], kfr[3], kfr[4]};

    const float2* gb = in + (size_t)b * CELLS;
    for (int li = tid; li < NIN; li += 256) {
        int iy = li / (TI * GZ);
        int r  = li - iy * (TI * GZ);
        int ix = r / GZ;
        int z  = r - ix * GZ;
        int gy = ty0 - 2 + iy;
        int gx = tx0 - 2 + ix;
        float2 v; v.x = 0.f; v.y = 0.f;
        if (gy >= 0 && gy < GH && gx >= 0 && gx < GW)
            v = gb[((size_t)gy * GW + gx) * GZ + z];
        sbin[li] = v;
    }
    __syncthreads();

    for (int o = tid; o < NTMP; o += 256) {
        int oy = o / (TI * GZ);
        int r  = o - oy * (TI * GZ);
        float2 a; a.x = 0.f; a.y = 0.f;
        #pragma unroll
        for (int t = 0; t < 5; ++t) {
            float2 g = sbin[(oy + t) * (TI * GZ) + r];
            a.x += ks[t] * g.x;
            a.y += ks[t] * g.y;
        }
        stmp[o] = a;
    }
    __syncthreads();

    for (int o = tid; o < NOUT; o += 256) {
        int oy = o / (TO * GZ);
        int r  = o - oy * (TO * GZ);
        int ox = r / GZ;
        int z  = r - ox * GZ;
        float2 a; a.x = 0.f; a.y = 0.f;
        #pragma unroll
        for (int t = 0; t < 5; ++t) {
            float2 g = stmp[(oy * TI + ox + t) * GZ + z];
            a.x += ks[t] * g.x;
            a.y += ks[t] * g.y;
        }
        sbin[o] = a;
    }
    __syncthreads();

    // z blur + transposed store: [gy][z][gx], gx fastest within a wave
    float2* ob = out + (size_t)b * CELLS;
    for (int o = tid; o < NOUT; o += 256) {
        int oy = o / (GZ * TO);
        int r2 = o - oy * (GZ * TO);
        int z  = r2 / TO;
        int ox = r2 - z * TO;
        int gy = ty0 + oy;
        int gx = tx0 + ox;
        if (gy < GH && gx < GW) {
            int cb = (oy * TO + ox) * GZ;
            float2 a; a.x = 0.f; a.y = 0.f;
            #pragma unroll
            for (int t = 0; t < 5; ++t) {
                int zz = z + t - 2;
                if (zz >= 0 && zz < GZ) {
                    float2 g = sbin[cb + zz];
                    a.x += kr[t] * g.x;
                    a.y += kr[t] * g.y;
                }
            }
            ob[((size_t)gy * GZ + z) * GW + gx] = a;
        }
    }
}

// ---- slice: grid rows in LDS as [z][r][x0pad] float2 ----
// Staging: linear global read, lane-consecutive x0 writes (conflict-free).
// Reads: bank-pair = (x0v + 8r) % 16, independent of random z0 (conflict-free);
// adjacent-x corners merge into ds_read2_b64.
#define XP2   136                 // padded x0 extent (f2); 136 % 16 == 8
#define RST   XP2                 // r stride (f2)
#define ZST   (2*XP2)             // z stride (f2) = 272 (== 0 mod 16)

__global__ __launch_bounds__(256) void slice_rows_kernel(
    const float* __restrict__ img, const float2* __restrict__ grid,
    float* __restrict__ out, int imgBase)
{
    __shared__ float2 sg[GZ * ZST];   // 17*272 f2 = 36992 B

    int tid = threadIdx.x;
    int k   = blockIdx.x;    // 0..127 (8-pixel-row group)
    int b   = blockIdx.y;

    const float2* gsrc = grid + (size_t)b * CELLS + (size_t)k * ROWSZ;
    for (int i = tid; i < 2 * ROWSZ; i += 256) {
        int r   = i / ROWSZ;
        int rem = i - r * ROWSZ;
        int z   = rem / GW;
        int x0  = rem - z * GW;
        sg[z * ZST + r * RST + x0] = gsrc[i];
    }
    __syncthreads();

    int x   = tid << 2;          // 4 px per thread per row
    int x0v = tid >> 1;          // x>>3, constant across the quad
    float txb = (float)(x & 7) * 0.125f;

    size_t rowBase = (size_t)(imgBase + b) * (HDIM * WDIM) + (size_t)(k << 3) * WDIM + x;

    #pragma unroll
    for (int r = 0; r < 8; ++r) {
        size_t pixBase = rowBase + (size_t)r * WDIM;
        float4 v4 = *(const float4*)(img + pixBase);
        float ty = (float)r * 0.125f;
        float wy0 = 1.f - ty, wy1 = ty;

        float vv[4] = {v4.x, v4.y, v4.z, v4.w};
        float rr[4];
        #pragma unroll
        for (int j = 0; j < 4; ++j) {
            float v  = vv[j];
            float fz = fminf(fmaxf(v * 15.0f, 0.0f), 15.0f);
            float zf = floorf(fz);
            int   z0 = (int)zf;
            float tz = fz - zf;
            float tx = txb + (float)j * 0.125f;
            float wx0 = 1.f - tx, wx1 = tx;
            float wz0 = 1.f - tz, wz1 = tz;

            int base = z0 * ZST + x0v;
            float2 g000 = sg[base];                // y0 x0 z0
            float2 g010 = sg[base + 1];            // y0 x1 z0
            float2 g100 = sg[base + RST];          // y1 x0 z0
            float2 g110 = sg[base + RST + 1];      // y1 x1 z0
            float2 g001 = sg[base + ZST];          // y0 x0 z1
            float2 g011 = sg[base + ZST + 1];      // y0 x1 z1
            float2 g101 = sg[base + ZST + RST];    // y1 x0 z1
            float2 g111 = sg[base + ZST + RST + 1];// y1 x1 z1

            float ov = 0.f, ow = 0.f, w;
            w = wy0 * wx0 * wz0; ov += w * g000.x; ow += w * g000.y;
            w = wy0 * wx0 * wz1; ov += w * g001.x; ow += w * g001.y;
            w = wy0 * wx1 * wz0; ov += w * g010.x; ow += w * g010.y;
            w = wy0 * wx1 * wz1; ov += w * g011.x; ow += w * g011.y;
            w = wy1 * wx0 * wz0; ov += w * g100.x; ow += w * g100.y;
            w = wy1 * wx0 * wz1; ov += w * g101.x; ow += w * g101.y;
            w = wy1 * wx1 * wz0; ov += w * g110.x; ow += w * g110.y;
            w = wy1 * wx1 * wz1; ov += w * g111.x; ow += w * g111.y;
            rr[j] = ov / (ow + EPSV);
        }
        float4 r4; r4.x = rr[0]; r4.y = rr[1]; r4.z = rr[2]; r4.w = rr[3];
        *(float4*)(out + pixBase) = r4;
    }
}

extern "C" void kernel_launch(void* const* d_in, const int* in_sizes, int n_in,
                              void* d_out, int out_size, void* d_ws, size_t ws_size,
                              hipStream_t stream)
{
    const float* img = (const float*)d_in[0];
    const float* fs  = (const float*)d_in[2];
    const float* fr  = (const float*)d_in[3];
    float* out = (float*)d_out;

    int nImgTotal = in_sizes[0] / (HDIM * WDIM);   // 12
    size_t perImgBytes = (size_t)CELLS * 2 * sizeof(float);

    int maxChunk = (int)(ws_size / (2 * perImgBytes));
    if (maxChunk < 1) return;
    if (maxChunk > nImgTotal) maxChunk = nImgTotal;

    const int tilesPerDim = (GH + TO - 1) / TO;    // 11

    for (int base = 0; base < nImgTotal; base += maxChunk) {
        int c = nImgTotal - base;
        if (c > maxChunk) c = maxChunk;

        float* A = (float*)d_ws;
        float* B = A + (size_t)c * CELLS * 2;

        int nCells = c * GH * GW;
        int colBlocks = (nCells + 31) / 32;        // 32 cells per 64-thread block
        splat_gather_kernel<<<colBlocks, 64, 0, stream>>>(img, A, c, base);

        dim3 bgrid(tilesPerDim, tilesPerDim, c);
        blur_fused_kernel<<<bgrid, 256, 0, stream>>>((const float2*)A, (float2*)B, fs, fr);

        dim3 sgrid(HDIM / 8, c);
        slice_rows_kernel<<<sgrid, 256, 0, stream>>>(img, (const float2*)B, out, base);
    }
}

// Round 11
// 106.209 us; speedup vs baseline: 1.2098x; 1.2098x over previous
//
#include <hip/hip_runtime.h>

#define S_SIGMA 8
#define NBINS   16
#define HDIM    1024
#define WDIM    1024
#define GH      129   // (1024-1)/8 + 2
#define GW      129
#define GZ      17    // NBINS + 1
#define CELLS   (GH*GW*GZ)   // 282897 cells per image
#define ROWSZ   (GW*GZ)      // 2193 float2 per grid row (either layout)
#define EPSV    1e-8f
#define FIXS    1048576.0f   // 2^20 fixed-point scale for val accumulation
#define FIXI    (1.0f/1048576.0f)

// ---- gather splat: one thread per cell; fixed-point LDS histograms ----
// Integer LDS atomicAdd = native fire-and-forget ds_add_u32 (no RMW chain,
// no CAS loop, no VALU select tree - lessons of rounds 6/7/10).
// val quantized to 2^-20 (sum <= 81*2^20 < 2^27); counts exact.
__global__ __launch_bounds__(64) void splat_gather_kernel(
    const float* __restrict__ img, float* __restrict__ grid, int nImg, int imgBase)
{
    __shared__ unsigned lval[16 * 64];   // [gz][tid], bank = tid%32, 2-way free
    __shared__ unsigned lwt [16 * 64];

    int tid = threadIdx.x;
    int idx = blockIdx.x * 64 + tid;
    int total = nImg * GH * GW;

    #pragma unroll
    for (int z = 0; z < 16; ++z) { lval[z * 64 + tid] = 0u; lwt[z * 64 + tid] = 0u; }

    if (idx < total) {
        int b   = idx / (GH * GW);
        int rem = idx - b * (GH * GW);
        int gy  = rem / GW;
        int gx  = rem - gy * GW;
        const float* ib = img + (size_t)(imgBase + b) * (HDIM * WDIM);

        bool interior = (gx >= 1) & (gx <= 127) & (gy >= 1) & (gy <= 127);
        if (interior) {
            int py = gy & 1, px = gx & 1;
            int ylo = 8 * gy - 4 + py;
            int nr  = 9 - 2 * py;
            int ax  = 8 * gx - 4;           // 4-aligned -> 16B float4 loads
            for (int r = 0; r < nr; ++r) {
                const float* rp = ib + (size_t)(ylo + r) * WDIM + ax;
                float4 A = *(const float4*)rp;
                float4 B = *(const float4*)(rp + 4);
                float  cv = rp[8];
                float e7[7] = {A.y, A.z, A.w, B.x, B.y, B.z, B.w};
                #pragma unroll
                for (int j = 0; j < 7; ++j) {
                    float v = e7[j];
                    int gz = min(max((int)rintf(v * 15.0f), 0), 15);
                    atomicAdd(&lval[gz * 64 + tid], (unsigned)rintf(v * FIXS));
                    atomicAdd(&lwt [gz * 64 + tid], 1u);
                }
                if (!px) {   // even gx also owns A.x and cv
                    int gz = min(max((int)rintf(A.x * 15.0f), 0), 15);
                    atomicAdd(&lval[gz * 64 + tid], (unsigned)rintf(A.x * FIXS));
                    atomicAdd(&lwt [gz * 64 + tid], 1u);
                    gz = min(max((int)rintf(cv * 15.0f), 0), 15);
                    atomicAdd(&lval[gz * 64 + tid], (unsigned)rintf(cv * FIXS));
                    atomicAdd(&lwt [gz * 64 + tid], 1u);
                }
            }
        } else {
            int ylo = max(0, 8 * gy - 4 + (gy & 1));
            int yhi = min(HDIM - 1, 8 * gy + 4 - (gy & 1));
            int xlo = max(0, 8 * gx - 4 + (gx & 1));
            int xhi = min(WDIM - 1, 8 * gx + 4 - (gx & 1));
            for (int y = ylo; y <= yhi; ++y) {
                const float* row = ib + (size_t)y * WDIM;
                for (int x = xlo; x <= xhi; ++x) {
                    float v = row[x];
                    int gz = min(max((int)rintf(v * 15.0f), 0), 15);
                    atomicAdd(&lval[gz * 64 + tid], (unsigned)rintf(v * FIXS));
                    atomicAdd(&lwt [gz * 64 + tid], 1u);
                }
            }
        }

        // writeout (same thread's column; compiler inserts the lgkm wait)
        float2* dst = (float2*)grid + (size_t)idx * GZ;
        #pragma unroll
        for (int z = 0; z < 16; ++z) {
            float2 o;
            o.x = (float)lval[z * 64 + tid] * FIXI;
            o.y = (float)lwt [z * 64 + tid];
            dst[z] = o;
        }
        float2 zero; zero.x = 0.f; zero.y = 0.f;
        dst[16] = zero;
    }
}

// ---- fused y+x+z blur, LDS tiled; OUTPUT TRANSPOSED to [gy][z][gx] ----
#define TO 12
#define TI 16
#define NIN  (TI*TI*GZ)    // 4352
#define NTMP (TO*TI*GZ)    // 3264
#define NOUT (TO*TO*GZ)    // 2448

__global__ __launch_bounds__(256) void blur_fused_kernel(
    const float2* __restrict__ in, float2* __restrict__ out,
    const float* __restrict__ kfs, const float* __restrict__ kfr)
{
    __shared__ float2 sbin[NIN];
    __shared__ float2 stmp[NTMP];

    int tid = threadIdx.x;
    int tx0 = blockIdx.x * TO;
    int ty0 = blockIdx.y * TO;
    int b   = blockIdx.z;

    float ks[5] = {kfs[0], kfs[1], kfs[2], kfs[3], kfs[4]};
    float kr[5] = {kfr[0], kfr[1], kfr[2], kfr[3], kfr[4]};

    const float2* gb = in + (size_t)b * CELLS;
    for (int li = tid; li < NIN; li += 256) {
        int iy = li / (TI * GZ);
        int r  = li - iy * (TI * GZ);
        int ix = r / GZ;
        int z  = r - ix * GZ;
        int gy = ty0 - 2 + iy;
        int gx = tx0 - 2 + ix;
        float2 v; v.x = 0.f; v.y = 0.f;
        if (gy >= 0 && gy < GH && gx >= 0 && gx < GW)
            v = gb[((size_t)gy * GW + gx) * GZ + z];
        sbin[li] = v;
    }
    __syncthreads();

    for (int o = tid; o < NTMP; o += 256) {
        int oy = o / (TI * GZ);
        int r  = o - oy * (TI * GZ);
        float2 a; a.x = 0.f; a.y = 0.f;
        #pragma unroll
        for (int t = 0; t < 5; ++t) {
            float2 g = sbin[(oy + t) * (TI * GZ) + r];
            a.x += ks[t] * g.x;
            a.y += ks[t] * g.y;
        }
        stmp[o] = a;
    }
    __syncthreads();

    for (int o = tid; o < NOUT; o += 256) {
        int oy = o / (TO * GZ);
        int r  = o - oy * (TO * GZ);
        int ox = r / GZ;
        int z  = r - ox * GZ;
        float2 a; a.x = 0.f; a.y = 0.f;
        #pragma unroll
        for (int t = 0; t < 5; ++t) {
            float2 g = stmp[(oy * TI + ox + t) * GZ + z];
            a.x += ks[t] * g.x;
            a.y += ks[t] * g.y;
        }
        sbin[o] = a;
    }
    __syncthreads();

    // z blur + transposed store: [gy][z][gx], gx fastest within a wave
    float2* ob = out + (size_t)b * CELLS;
    for (int o = tid; o < NOUT; o += 256) {
        int oy = o / (GZ * TO);
        int r2 = o - oy * (GZ * TO);
        int z  = r2 / TO;
        int ox = r2 - z * TO;
        int gy = ty0 + oy;
        int gx = tx0 + ox;
        if (gy < GH && gx < GW) {
            int cb = (oy * TO + ox) * GZ;
            float2 a; a.x = 0.f; a.y = 0.f;
            #pragma unroll
            for (int t = 0; t < 5; ++t) {
                int zz = z + t - 2;
                if (zz >= 0 && zz < GZ) {
                    float2 g = sbin[cb + zz];
                    a.x += kr[t] * g.x;
                    a.y += kr[t] * g.y;
                }
            }
            ob[((size_t)gy * GZ + z) * GW + gx] = a;
        }
    }
}

// ---- slice: grid rows in LDS as [z][r][x0pad] float2 (conflict-free) ----
#define XP2   136                 // padded x0 extent (f2); 136 % 16 == 8
#define RST   XP2                 // r stride (f2)
#define ZST   (2*XP2)             // z stride (f2) = 272 (== 0 mod 16)

__global__ __launch_bounds__(256) void slice_rows_kernel(
    const float* __restrict__ img, const float2* __restrict__ grid,
    float* __restrict__ out, int imgBase)
{
    __shared__ float2 sg[GZ * ZST];   // 17*272 f2 = 36992 B

    int tid = threadIdx.x;
    int k   = blockIdx.x;    // 0..127 (8-pixel-row group)
    int b   = blockIdx.y;

    const float2* gsrc = grid + (size_t)b * CELLS + (size_t)k * ROWSZ;
    for (int i = tid; i < 2 * ROWSZ; i += 256) {
        int r   = i / ROWSZ;
        int rem = i - r * ROWSZ;
        int z   = rem / GW;
        int x0  = rem - z * GW;
        sg[z * ZST + r * RST + x0] = gsrc[i];
    }
    __syncthreads();

    int x   = tid << 2;          // 4 px per thread per row
    int x0v = tid >> 1;          // x>>3, constant across the quad
    float txb = (float)(x & 7) * 0.125f;

    size_t rowBase = (size_t)(imgBase + b) * (HDIM * WDIM) + (size_t)(k << 3) * WDIM + x;

    #pragma unroll
    for (int r = 0; r < 8; ++r) {
        size_t pixBase = rowBase + (size_t)r * WDIM;
        float4 v4 = *(const float4*)(img + pixBase);
        float ty = (float)r * 0.125f;
        float wy0 = 1.f - ty, wy1 = ty;

        float vv[4] = {v4.x, v4.y, v4.z, v4.w};
        float rr[4];
        #pragma unroll
        for (int j = 0; j < 4; ++j) {
            float v  = vv[j];
            float fz = fminf(fmaxf(v * 15.0f, 0.0f), 15.0f);
            float zf = floorf(fz);
            int   z0 = (int)zf;
            float tz = fz - zf;
            float tx = txb + (float)j * 0.125f;
            float wx0 = 1.f - tx, wx1 = tx;
            float wz0 = 1.f - tz, wz1 = tz;

            int base = z0 * ZST + x0v;
            float2 g000 = sg[base];                // y0 x0 z0
            float2 g010 = sg[base + 1];            // y0 x1 z0
            float2 g100 = sg[base + RST];          // y1 x0 z0
            float2 g110 = sg[base + RST + 1];      // y1 x1 z0
            float2 g001 = sg[base + ZST];          // y0 x0 z1
            float2 g011 = sg[base + ZST + 1];      // y0 x1 z1
            float2 g101 = sg[base + ZST + RST];    // y1 x0 z1
            float2 g111 = sg[base + ZST + RST + 1];// y1 x1 z1

            float ov = 0.f, ow = 0.f, w;
            w = wy0 * wx0 * wz0; ov += w * g000.x; ow += w * g000.y;
            w = wy0 * wx0 * wz1; ov += w * g001.x; ow += w * g001.y;
            w = wy0 * wx1 * wz0; ov += w * g010.x; ow += w * g010.y;
            w = wy0 * wx1 * wz1; ov += w * g011.x; ow += w * g011.y;
            w = wy1 * wx0 * wz0; ov += w * g100.x; ow += w * g100.y;
            w = wy1 * wx0 * wz1; ov += w * g101.x; ow += w * g101.y;
            w = wy1 * wx1 * wz0; ov += w * g110.x; ow += w * g110.y;
            w = wy1 * wx1 * wz1; ov += w * g111.x; ow += w * g111.y;
            rr[j] = ov / (ow + EPSV);
        }
        float4 r4; r4.x = rr[0]; r4.y = rr[1]; r4.z = rr[2]; r4.w = rr[3];
        *(float4*)(out + pixBase) = r4;
    }
}

extern "C" void kernel_launch(void* const* d_in, const int* in_sizes, int n_in,
                              void* d_out, int out_size, void* d_ws, size_t ws_size,
                              hipStream_t stream)
{
    const float* img = (const float*)d_in[0];
    const float* fs  = (const float*)d_in[2];
    const float* fr  = (const float*)d_in[3];
    float* out = (float*)d_out;

    int nImgTotal = in_sizes[0] / (HDIM * WDIM);   // 12
    size_t perImgBytes = (size_t)CELLS * 2 * sizeof(float);

    int maxChunk = (int)(ws_size / (2 * perImgBytes));
    if (maxChunk < 1) return;
    if (maxChunk > nImgTotal) maxChunk = nImgTotal;

    const int tilesPerDim = (GH + TO - 1) / TO;    // 11

    for (int base = 0; base < nImgTotal; base += maxChunk) {
        int c = nImgTotal - base;
        if (c > maxChunk) c = maxChunk;

        float* A = (float*)d_ws;
        float* B = A + (size_t)c * CELLS * 2;

        int nCells = c * GH * GW;
        int colBlocks = (nCells + 63) / 64;        // one thread per cell
        splat_gather_kernel<<<colBlocks, 64, 0, stream>>>(img, A, c, base);

        dim3 bgrid(tilesPerDim, tilesPerDim, c);
        blur_fused_kernel<<<bgrid, 256, 0, stream>>>((const float2*)A, (float2*)B, fs, fr);

        dim3 sgrid(HDIM / 8, c);
        slice_rows_kernel<<<sgrid, 256, 0, stream>>>(img, (const float2*)B, out, base);
    }
}

// Round 12
// 93.429 us; speedup vs baseline: 1.3753x; 1.1368x over previous
//
#include <hip/hip_runtime.h>

#define S_SIGMA 8
#define NBINS   16
#define HDIM    1024
#define WDIM    1024
#define GH      129   // (1024-1)/8 + 2
#define GW      129
#define GZ      17    // NBINS + 1
#define CELLS   (GH*GW*GZ)   // 282897 cells per image
#define ROWSZ   (GW*GZ)      // 2193 float2 per grid row (either layout)
#define EPSV    1e-8f
#define FIXS    1048576.0f   // 2^20 fixed-point scale for val accumulation
#define FIXI    (1.0f/1048576.0f)

// ---- gather splat: 4 threads per cell, fire-and-forget ds_add_u32 ----
// 256-thread block = 64 cells; wave q handles rows q::4 of each cell's
// footprint. Integer LDS atomics allow column sharing across waves.
__global__ __launch_bounds__(256) void splat_gather_kernel(
    const float* __restrict__ img, float* __restrict__ grid, int nImg, int imgBase)
{
    __shared__ unsigned lval[16 * 64];   // [gz][cell], bank = cell%32, 2-way free
    __shared__ unsigned lwt [16 * 64];

    int tid = threadIdx.x;
    int c   = tid & 63;          // cell slot
    int q   = tid >> 6;          // row quarter (constant per wave)
    int cellIdx = blockIdx.x * 64 + c;
    int total = nImg * GH * GW;

    for (int i = tid; i < 16 * 64; i += 256) { lval[i] = 0u; lwt[i] = 0u; }
    __syncthreads();

    if (cellIdx < total) {
        int b   = cellIdx / (GH * GW);
        int rem = cellIdx - b * (GH * GW);
        int gy  = rem / GW;
        int gx  = rem - gy * GW;
        const float* ib = img + (size_t)(imgBase + b) * (HDIM * WDIM);

        bool interior = (gx >= 1) & (gx <= 127) & (gy >= 1) & (gy <= 127);
        if (interior) {
            int py = gy & 1, px = gx & 1;
            int ylo = 8 * gy - 4 + py;
            int nr  = 9 - 2 * py;
            int ax  = 8 * gx - 4;           // 4-aligned -> 16B float4 loads
            for (int r = q; r < nr; r += 4) {
                const float* rp = ib + (size_t)(ylo + r) * WDIM + ax;
                float4 A = *(const float4*)rp;
                float4 B = *(const float4*)(rp + 4);
                float  cv = rp[8];
                float e7[7] = {A.y, A.z, A.w, B.x, B.y, B.z, B.w};
                #pragma unroll
                for (int j = 0; j < 7; ++j) {
                    float v = e7[j];
                    int gz = min(max((int)rintf(v * 15.0f), 0), 15);
                    atomicAdd(&lval[gz * 64 + c], (unsigned)rintf(v * FIXS));
                    atomicAdd(&lwt [gz * 64 + c], 1u);
                }
                if (!px) {   // even gx also owns A.x and cv
                    int gz = min(max((int)rintf(A.x * 15.0f), 0), 15);
                    atomicAdd(&lval[gz * 64 + c], (unsigned)rintf(A.x * FIXS));
                    atomicAdd(&lwt [gz * 64 + c], 1u);
                    gz = min(max((int)rintf(cv * 15.0f), 0), 15);
                    atomicAdd(&lval[gz * 64 + c], (unsigned)rintf(cv * FIXS));
                    atomicAdd(&lwt [gz * 64 + c], 1u);
                }
            }
        } else {
            int ylo = max(0, 8 * gy - 4 + (gy & 1));
            int yhi = min(HDIM - 1, 8 * gy + 4 - (gy & 1));
            int xlo = max(0, 8 * gx - 4 + (gx & 1));
            int xhi = min(WDIM - 1, 8 * gx + 4 - (gx & 1));
            for (int y = ylo + q; y <= yhi; y += 4) {
                const float* row = ib + (size_t)y * WDIM;
                for (int x = xlo; x <= xhi; ++x) {
                    float v = row[x];
                    int gz = min(max((int)rintf(v * 15.0f), 0), 15);
                    atomicAdd(&lval[gz * 64 + c], (unsigned)rintf(v * FIXS));
                    atomicAdd(&lwt [gz * 64 + c], 1u);
                }
            }
        }
    }
    __syncthreads();

    // writeout: thread (q,c) writes z in [4q, 4q+4) (+ z=16 zero for q==3)
    if (cellIdx < total) {
        float2* dst = (float2*)grid + (size_t)cellIdx * GZ;
        int zlo = q * 4;
        int zhi = (q == 3) ? 17 : zlo + 4;
        for (int z = zlo; z < zhi; ++z) {
            float2 o;
            if (z == 16) { o.x = 0.f; o.y = 0.f; }
            else {
                o.x = (float)lval[z * 64 + c] * FIXI;
                o.y = (float)lwt [z * 64 + c];
            }
            dst[z] = o;
        }
    }
}

// ---- fused y+x+z blur; y-blur intermediate in REGISTERS (no stmp) ----
// LDS = 34.8 KB -> 4 blocks/CU (was 60.9 KB / 2 blocks).
#define TO 12
#define TI 16
#define NIN  (TI*TI*GZ)    // 4352
#define NTMP (TO*TI*GZ)    // 3264
#define NOUT (TO*TO*GZ)    // 2448
#define NTI  13            // ceil(NTMP/256)
#define NXI  10            // ceil(NOUT/256)

__global__ __launch_bounds__(256) void blur_fused_kernel(
    const float2* __restrict__ in, float2* __restrict__ out,
    const float* __restrict__ kfs, const float* __restrict__ kfr)
{
    __shared__ float2 sbin[NIN];   // input tile; reused for stmp, then xb

    int tid = threadIdx.x;
    int tx0 = blockIdx.x * TO;
    int ty0 = blockIdx.y * TO;
    int b   = blockIdx.z;

    float ks[5] = {kfs[0], kfs[1], kfs[2], kfs[3], kfs[4]};
    float kr[5] = {kfr[0], kfr[1], kfr[2], kfr[3], kfr[4]};

    const float2* gb = in + (size_t)b * CELLS;
    for (int li = tid; li < NIN; li += 256) {
        int iy = li / (TI * GZ);
        int r  = li - iy * (TI * GZ);
        int ix = r / GZ;
        int z  = r - ix * GZ;
        int gy = ty0 - 2 + iy;
        int gx = tx0 - 2 + ix;
        float2 v; v.x = 0.f; v.y = 0.f;
        if (gy >= 0 && gy < GH && gx >= 0 && gx < GW)
            v = gb[((size_t)gy * GW + gx) * GZ + z];
        sbin[li] = v;
    }
    __syncthreads();

    // y blur into registers (static indexing - rule #20)
    float2 rt[NTI];
    #pragma unroll
    for (int it = 0; it < NTI; ++it) {
        int o = tid + it * 256;
        float2 a; a.x = 0.f; a.y = 0.f;
        if (o < NTMP) {
            int oy = o / (TI * GZ);
            int r  = o - oy * (TI * GZ);
            #pragma unroll
            for (int t = 0; t < 5; ++t) {
                float2 g = sbin[(oy + t) * (TI * GZ) + r];
                a.x += ks[t] * g.x;
                a.y += ks[t] * g.y;
            }
        }
        rt[it] = a;
    }
    __syncthreads();
    #pragma unroll
    for (int it = 0; it < NTI; ++it) {
        int o = tid + it * 256;
        if (o < NTMP) sbin[o] = rt[it];   // sbin now holds stmp[oy][ix][z]
    }
    __syncthreads();

    // x blur into registers
    float2 rx[NXI];
    #pragma unroll
    for (int it = 0; it < NXI; ++it) {
        int o = tid + it * 256;
        float2 a; a.x = 0.f; a.y = 0.f;
        if (o < NOUT) {
            int oy = o / (TO * GZ);
            int r  = o - oy * (TO * GZ);
            int ox = r / GZ;
            int z  = r - ox * GZ;
            #pragma unroll
            for (int t = 0; t < 5; ++t) {
                float2 g = sbin[(oy * TI + ox + t) * GZ + z];
                a.x += ks[t] * g.x;
                a.y += ks[t] * g.y;
            }
        }
        rx[it] = a;
    }
    __syncthreads();
    #pragma unroll
    for (int it = 0; it < NXI; ++it) {
        int o = tid + it * 256;
        if (o < NOUT) sbin[o] = rx[it];   // sbin now holds xb[oy][ox][z]
    }
    __syncthreads();

    // z blur + transposed store: [gy][z][gx]
    float2* ob = out + (size_t)b * CELLS;
    for (int o = tid; o < NOUT; o += 256) {
        int oy = o / (GZ * TO);
        int r2 = o - oy * (GZ * TO);
        int z  = r2 / TO;
        int ox = r2 - z * TO;
        int gy = ty0 + oy;
        int gx = tx0 + ox;
        if (gy < GH && gx < GW) {
            int cb = (oy * TO + ox) * GZ;
            float2 a; a.x = 0.f; a.y = 0.f;
            #pragma unroll
            for (int t = 0; t < 5; ++t) {
                int zz = z + t - 2;
                if (zz >= 0 && zz < GZ) {
                    float2 g = sbin[cb + zz];
                    a.x += kr[t] * g.x;
                    a.y += kr[t] * g.y;
                }
            }
            ob[((size_t)gy * GZ + z) * GW + gx] = a;
        }
    }
}

// ---- slice: grid rows in LDS as [z][r][x0pad] float2 (conflict-free) ----
#define XP2   136                 // padded x0 extent (f2); 136 % 16 == 8
#define RST   XP2                 // r stride (f2)
#define ZST   (2*XP2)             // z stride (f2) = 272 (== 0 mod 16)

__global__ __launch_bounds__(256) void slice_rows_kernel(
    const float* __restrict__ img, const float2* __restrict__ grid,
    float* __restrict__ out, int imgBase)
{
    __shared__ float2 sg[GZ * ZST];   // 17*272 f2 = 36992 B

    int tid = threadIdx.x;
    int k   = blockIdx.x;    // 0..127 (8-pixel-row group)
    int b   = blockIdx.y;

    const float2* gsrc = grid + (size_t)b * CELLS + (size_t)k * ROWSZ;
    for (int i = tid; i < 2 * ROWSZ; i += 256) {
        int r   = i / ROWSZ;
        int rem = i - r * ROWSZ;
        int z   = rem / GW;
        int x0  = rem - z * GW;
        sg[z * ZST + r * RST + x0] = gsrc[i];
    }
    __syncthreads();

    int x   = tid << 2;          // 4 px per thread per row
    int x0v = tid >> 1;          // x>>3, constant across the quad
    float txb = (float)(x & 7) * 0.125f;

    size_t rowBase = (size_t)(imgBase + b) * (HDIM * WDIM) + (size_t)(k << 3) * WDIM + x;

    #pragma unroll
    for (int r = 0; r < 8; ++r) {
        size_t pixBase = rowBase + (size_t)r * WDIM;
        float4 v4 = *(const float4*)(img + pixBase);
        float ty = (float)r * 0.125f;
        float wy0 = 1.f - ty, wy1 = ty;

        float vv[4] = {v4.x, v4.y, v4.z, v4.w};
        float rr[4];
        #pragma unroll
        for (int j = 0; j < 4; ++j) {
            float v  = vv[j];
            float fz = fminf(fmaxf(v * 15.0f, 0.0f), 15.0f);
            float zf = floorf(fz);
            int   z0 = (int)zf;
            float tz = fz - zf;
            float tx = txb + (float)j * 0.125f;
            float wx0 = 1.f - tx, wx1 = tx;
            float wz0 = 1.f - tz, wz1 = tz;

            int base = z0 * ZST + x0v;
            float2 g000 = sg[base];                // y0 x0 z0
            float2 g010 = sg[base + 1];            // y0 x1 z0
            float2 g100 = sg[base + RST];          // y1 x0 z0
            float2 g110 = sg[base + RST + 1];      // y1 x1 z0
            float2 g001 = sg[base + ZST];          // y0 x0 z1
            float2 g011 = sg[base + ZST + 1];      // y0 x1 z1
            float2 g101 = sg[base + ZST + RST];    // y1 x0 z1
            float2 g111 = sg[base + ZST + RST + 1];// y1 x1 z1

            float ov = 0.f, ow = 0.f, w;
            w = wy0 * wx0 * wz0; ov += w * g000.x; ow += w * g000.y;
            w = wy0 * wx0 * wz1; ov += w * g001.x; ow += w * g001.y;
            w = wy0 * wx1 * wz0; ov += w * g010.x; ow += w * g010.y;
            w = wy0 * wx1 * wz1; ov += w * g011.x; ow += w * g011.y;
            w = wy1 * wx0 * wz0; ov += w * g100.x; ow += w * g100.y;
            w = wy1 * wx0 * wz1; ov += w * g101.x; ow += w * g101.y;
            w = wy1 * wx1 * wz0; ov += w * g110.x; ow += w * g110.y;
            w = wy1 * wx1 * wz1; ov += w * g111.x; ow += w * g111.y;
            rr[j] = ov / (ow + EPSV);
        }
        float4 r4; r4.x = rr[0]; r4.y = rr[1]; r4.z = rr[2]; r4.w = rr[3];
        *(float4*)(out + pixBase) = r4;
    }
}

extern "C" void kernel_launch(void* const* d_in, const int* in_sizes, int n_in,
                              void* d_out, int out_size, void* d_ws, size_t ws_size,
                              hipStream_t stream)
{
    const float* img = (const float*)d_in[0];
    const float* fs  = (const float*)d_in[2];
    const float* fr  = (const float*)d_in[3];
    float* out = (float*)d_out;

    int nImgTotal = in_sizes[0] / (HDIM * WDIM);   // 12
    size_t perImgBytes = (size_t)CELLS * 2 * sizeof(float);

    int maxChunk = (int)(ws_size / (2 * perImgBytes));
    if (maxChunk < 1) return;
    if (maxChunk > nImgTotal) maxChunk = nImgTotal;

    const int tilesPerDim = (GH + TO - 1) / TO;    // 11

    for (int base = 0; base < nImgTotal; base += maxChunk) {
        int c = nImgTotal - base;
        if (c > maxChunk) c = maxChunk;

        float* A = (float*)d_ws;
        float* B = A + (size_t)c * CELLS * 2;

        int nCells = c * GH * GW;
        int cellBlocks = (nCells + 63) / 64;       // 64 cells per 256-thread block
        splat_gather_kernel<<<cellBlocks, 256, 0, stream>>>(img, A, c, base);

        dim3 bgrid(tilesPerDim, tilesPerDim, c);
        blur_fused_kernel<<<bgrid, 256, 0, stream>>>((const float2*)A, (float2*)B, fs, fr);

        dim3 sgrid(HDIM / 8, c);
        slice_rows_kernel<<<sgrid, 256, 0, stream>>>(img, (const float2*)B, out, base);
    }
}